// Round 4
// baseline (4333.566 us; speedup 1.0000x reference)
//
#include <hip/hip_runtime.h>
#include <cstddef>

// LSTM: x[64,512,512] f32, kernel[512,4096] f32, rec_kernel[1024,4096] f32,
// bias[4096] f32 -> h_last[64,1024] f32.
// Persistent kernel, weights stationary in VGPRs (bf16), fused x-projection.
// R5 (resubmitted; rounds 2-3 were infra failures): DATA-AS-FLAG. Published h
// is epoch-tagged per dword (h_bf16<<16 | epoch). Producer stores are
// fire-and-forget (no vmcnt drain, no flag store); consumers poll the tagged
// data directly with a masked retry loop. Collapses ~3 MALL round trips/step
// to ~1. Gate epilogue distributed across all 256 threads (1 u each).
// Double-buffered hx; dependence chain (publish t+2 requires consuming t+1
// from all mt-peers) prevents overwrite-before-read, so exact-equality tag
// poll is safe (no ABA, no deadlock).

namespace {
constexpr int cB = 64;
constexpr int cT = 512;
constexpr int cD = 512;
constexpr int cU = 1024;
constexpr int cG = 4096;   // 4*U
constexpr int NKC = 48;    // K/32 = 1536/32
constexpr int NBLK = 256;
constexpr int NT = 256;
constexpr int HSTR = 1032; // padded LDS h-row stride (bf16): 516 dwords, %32==4
}

typedef __attribute__((ext_vector_type(8))) short   short8;
typedef __attribute__((ext_vector_type(8))) __bf16  bf16x8;
typedef __attribute__((ext_vector_type(4))) float   f32x4;

__device__ inline short f2bf(float f) {
  unsigned u = __float_as_uint(f);
  u += 0x7fffu + ((u >> 16) & 1u);   // round-to-nearest-even
  return (short)(u >> 16);
}

__device__ inline f32x4 mfma16(short8 a, short8 b, f32x4 c) {
  return __builtin_amdgcn_mfma_f32_16x16x32_bf16(
      __builtin_bit_cast(bf16x8, a), __builtin_bit_cast(bf16x8, b), c, 0, 0, 0);
}

__device__ inline float sigm(float x) { return 1.0f / (1.0f + __expf(-x)); }
__device__ inline float tanh_(float x) {
  float a = fabsf(x);
  float e = __expf(-2.0f * a);
  float t = (1.0f - e) / (1.0f + e);
  return x < 0.0f ? -t : t;
}

__global__ __launch_bounds__(NT, 1) void lstm_persist(
    const float* __restrict__ x, const float* __restrict__ wk,
    const float* __restrict__ wr, const float* __restrict__ bias,
    float* __restrict__ out, short* __restrict__ xbf,
    unsigned* hx, unsigned* flags) {
  const int tid  = threadIdx.x;
  const int wave = tid >> 6;        // = gate id 0..3 (i,f,c,o)
  const int lane = tid & 63;
  const int n    = lane & 15;       // MFMA col within tile / A row m
  const int quad = lane >> 4;
  const int bid  = blockIdx.x;
  const int mt   = bid & 3;         // batch m-tile (16 rows each)
  const int cg   = bid >> 2;        // u-group 0..63 (16 u each)
  const int ub   = cg * 16;

  __shared__ short hlds[16 * HSTR]; // staged h rows (padded, ~33 KB)
  __shared__ float zsh[16 * 65];    // [row][gate*16+u], pad 65 = conflict-free

  // ---- phase 0: convert x to bf16 once (grid-stride) ----
  {
    const f32x4* xv = reinterpret_cast<const f32x4*>(x);
    short8* xo = reinterpret_cast<short8*>(xbf);
    const size_t nvec = (size_t)cB * cT * cD / 8;
    for (size_t i = (size_t)bid * NT + tid; i < nvec; i += (size_t)NBLK * NT) {
      f32x4 v0 = xv[2 * i];
      f32x4 v1 = xv[2 * i + 1];
      short8 s;
      s[0] = f2bf(v0[0]); s[1] = f2bf(v0[1]); s[2] = f2bf(v0[2]); s[3] = f2bf(v0[3]);
      s[4] = f2bf(v1[0]); s[5] = f2bf(v1[1]); s[6] = f2bf(v1[2]); s[7] = f2bf(v1[3]);
      xo[i] = s;
    }
  }

  // ---- load time-invariant W fragments into registers ----
  // B-frag layout (16x16x32 bf16): B[k][n], n = lane&15, k = quad*8 + j.
  short8 Bf[NKC];
  {
    const int col = wave * cU + ub + n;     // column in the 4096 gate dim
    #pragma unroll
    for (int kc = 0; kc < NKC; ++kc) {
      const int k0 = kc * 32 + quad * 8;
      short8 b;
      #pragma unroll
      for (int j = 0; j < 8; ++j) {
        const int k = k0 + j;
        const float w = (k < cD) ? wk[(size_t)k * cG + col]
                                 : wr[(size_t)(k - cD) * cG + col];
        b[j] = f2bf(w);
      }
      Bf[kc] = b;
    }
  }

  // ---- distributed epilogue mapping: thread -> (row, single u) ----
  const int erow = tid >> 4;        // 0..15
  const int eu   = tid & 15;        // 0..15
  const int hrow = mt * 16 + erow;  // global batch row this thread publishes
  const float bi  = bias[0 * cU + ub + eu];
  const float bff = bias[1 * cU + ub + eu];
  const float bc  = bias[2 * cU + ub + eu];
  const float bo  = bias[3 * cU + ub + eu];
  float cst = 0.0f;

  // A-frag addressing for x: A[m][k], m = lane&15 -> batch row, k = quad*8+j
  const int brow = mt * 16 + n;
  const short* xrow = xbf + (size_t)brow * cT * cD + quad * 8;

  // ---- initial full-grid barrier: xbf ready everywhere ----
  __builtin_amdgcn_fence(__ATOMIC_RELEASE, "agent");
  __syncthreads();
  if (tid == 0)
    __hip_atomic_store(flags + bid * 16, 1u, __ATOMIC_RELEASE,
                       __HIP_MEMORY_SCOPE_AGENT);
  if (wave == 0) {
    #pragma unroll
    for (int j = 0; j < 4; ++j) {
      const unsigned* fp = flags + (j * 64 + lane) * 16;
      while (__hip_atomic_load(fp, __ATOMIC_RELAXED,
                               __HIP_MEMORY_SCOPE_AGENT) < 1u) {}
    }
  }
  __syncthreads();
  __builtin_amdgcn_fence(__ATOMIC_ACQUIRE, "agent");

  unsigned* hlds32 = reinterpret_cast<unsigned*>(hlds);

  for (int t = 0; t < cT; ++t) {
    // x-part of K (h-independent) — overlaps the producer store flight
    f32x4 acc[4] = {{0,0,0,0},{0,0,0,0},{0,0,0,0},{0,0,0,0}};
    const short* xr = xrow + (size_t)t * cD;
    #pragma unroll
    for (int kc = 0; kc < 16; ++kc) {
      short8 af = *reinterpret_cast<const short8*>(xr + kc * 32);
      acc[kc & 3] = mfma16(af, Bf[kc], acc[kc & 3]);
    }

    if (t > 0) {
      // ---- poll epoch-tagged h directly (data IS the flag) ----
      // thread covers 32 8B chunks: 16 rows x 2 halves; each dword is
      // (h_bf16<<16 | epoch). Retry only stragglers.
      const unsigned ep = (unsigned)t;
      const unsigned long long* src =
          reinterpret_cast<const unsigned long long*>(hx) +
          (size_t)((t - 1) & 1) * 32768 + (size_t)(mt * 16) * 512 +
          (size_t)tid * 2;
      unsigned pend = 0xFFFFFFFFu;
      while (pend) {
        unsigned long long v[32];
        #pragma unroll
        for (int ci = 0; ci < 32; ++ci)
          if (pend & (1u << ci))
            v[ci] = __hip_atomic_load(src + (ci >> 1) * 512 + (ci & 1),
                                      __ATOMIC_RELAXED,
                                      __HIP_MEMORY_SCOPE_AGENT);
        #pragma unroll
        for (int ci = 0; ci < 32; ++ci)
          if (pend & (1u << ci)) {
            const unsigned lo = (unsigned)v[ci];
            const unsigned hi = (unsigned)(v[ci] >> 32);
            if ((lo & 0xFFFFu) == ep && (hi & 0xFFFFu) == ep) {
              pend &= ~(1u << ci);
              hlds32[(ci >> 1) * 516 + tid * 2 + (ci & 1)] =
                  (lo >> 16) | (hi & 0xFFFF0000u);
            }
          }
      }
      __syncthreads();

      // h-part MFMAs from LDS (A row = n, k = kc*32 + quad*8 + j)
      const short* hfrag = hlds + n * HSTR + quad * 8;
      #pragma unroll
      for (int kc = 0; kc < 32; ++kc) {
        short8 af = *reinterpret_cast<const short8*>(hfrag + kc * 32);
        acc[kc & 3] = mfma16(af, Bf[16 + kc], acc[kc & 3]);
      }
    }
    f32x4 z4 = (acc[0] + acc[1]) + (acc[2] + acc[3]);

    // C/D layout: col = lane&15, row = quad*4 + reg
    #pragma unroll
    for (int r = 0; r < 4; ++r)
      zsh[(quad * 4 + r) * 65 + wave * 16 + n] = z4[r];
    __syncthreads();

    // ---- distributed epilogue: every thread does 1 u ----
    // zsh(t) stays valid until zsh(t+1) write, which is gated by the t+1
    // poll (needs our own block's publishes) -> no extra barrier needed.
    const float* zr = zsh + erow * 65;
    const float ig = sigm(zr[eu]        + bi);
    const float fg = sigm(zr[16 + eu]   + bff);
    const float gg = tanh_(zr[32 + eu]  + bc);
    const float og = sigm(zr[48 + eu]   + bo);
    cst = fg * cst + ig * gg;
    const float h = og * tanh_(cst);

    if (t == cT - 1) {
      out[(size_t)hrow * cU + ub + eu] = h;
    } else {
      // fire-and-forget tagged publish; the store IS the signal
      const unsigned d =
          ((unsigned)(unsigned short)f2bf(h) << 16) | (unsigned)(t + 1);
      __hip_atomic_store(hx + (size_t)(t & 1) * 65536 + (size_t)hrow * 1024 +
                             ub + eu,
                         d, __ATOMIC_RELAXED, __HIP_MEMORY_SCOPE_AGENT);
    }
  }
}

extern "C" void kernel_launch(void* const* d_in, const int* in_sizes, int n_in,
                              void* d_out, int out_size, void* d_ws, size_t ws_size,
                              hipStream_t stream) {
  const float* x    = (const float*)d_in[0];
  const float* wk   = (const float*)d_in[1];
  const float* wr   = (const float*)d_in[2];
  const float* bias = (const float*)d_in[3];
  float* out = (float*)d_out;

  char* ws = (char*)d_ws;
  unsigned* flags = (unsigned*)ws;                 // 256 slots x 64B = 16 KB
  unsigned* hx = (unsigned*)(ws + 16384);          // 2 x [64][1024] dwords, 512 KB
  short* xbf = (short*)(ws + 16384 + 524288);      // x bf16, 32 MB

  // zero flags (startup barrier) + hx (tag 0 != any expected epoch 1..511;
  // also guards against stale tags from a previous call).
  hipMemsetAsync(ws, 0, 16384 + 524288, stream);

  lstm_persist<<<dim3(NBLK), dim3(NT), 0, stream>>>(
      x, wk, wr, bias, out, xbf, hx, flags);
}

// Round 6
// 2252.495 us; speedup vs baseline: 1.9239x; 1.9239x over previous
//
#include <hip/hip_runtime.h>
#include <cstddef>

// LSTM: x[64,512,512] f32, kernel[512,4096] f32, rec_kernel[1024,4096] f32,
// bias[4096] f32 -> h_last[64,1024] f32.
// R6 (resubmitted; round 5 was an infra failure): counter-arrival +
// register-direct h consumption.
//  - Waves split by K-slice (wave w owns kc === w mod 4, all 4 gates) so each
//    lane loads its h A-frag straight from MALL into registers (no LDS stage,
//    no bulk-read stage, no staging barrier). Partial gate sums reduced via
//    4-plane zsh.
//  - Arrival via 16 monotonic counters (4 per mt group, 16 producers each,
//    128B apart). Producer: store h (2B/thread) -> vmcnt(0) -> barrier ->
//    tid0 fetch_add. Consumer: 4 lanes/wave spin until all 4 counters reach
//    16*t. Tiny poll footprint (R5 lesson: distributed data-polling floods
//    the MALL).
//  - WAR-safe: poll(t) pass => every same-mt block's step-(t-1) add => its
//    reads of buf[t&1] preceded its stores+drain => overwrite at step t safe.

namespace {
constexpr int cB = 64;
constexpr int cT = 512;
constexpr int cD = 512;
constexpr int cU = 1024;
constexpr int cG = 4096;   // 4*U
constexpr int NBLK = 256;
constexpr int NT = 256;
}

typedef __attribute__((ext_vector_type(8))) short   short8;
typedef __attribute__((ext_vector_type(8))) __bf16  bf16x8;
typedef __attribute__((ext_vector_type(4))) float   f32x4;

__device__ inline short f2bf(float f) {
  unsigned u = __float_as_uint(f);
  u += 0x7fffu + ((u >> 16) & 1u);   // round-to-nearest-even
  return (short)(u >> 16);
}

__device__ inline f32x4 mfma16(short8 a, short8 b, f32x4 c) {
  return __builtin_amdgcn_mfma_f32_16x16x32_bf16(
      __builtin_bit_cast(bf16x8, a), __builtin_bit_cast(bf16x8, b), c, 0, 0, 0);
}

__device__ inline float sigm(float x) { return 1.0f / (1.0f + __expf(-x)); }
__device__ inline float tanh_(float x) {
  float a = fabsf(x);
  float e = __expf(-2.0f * a);
  float t = (1.0f - e) / (1.0f + e);
  return x < 0.0f ? -t : t;
}

__global__ __launch_bounds__(NT, 1) void lstm_persist(
    const float* __restrict__ x, const float* __restrict__ wk,
    const float* __restrict__ wr, const float* __restrict__ bias,
    float* __restrict__ out, short* __restrict__ xbf,
    short* hx, unsigned* cnt, unsigned* flags) {
  const int tid  = threadIdx.x;
  const int wv   = tid >> 6;        // wave = K-slice owner (kc === wv mod 4)
  const int lane = tid & 63;
  const int n    = lane & 15;       // MFMA A row m / C col
  const int quad = lane >> 4;
  const int bid  = blockIdx.x;
  const int mt   = bid & 3;         // batch m-tile (16 rows each)
  const int cg   = bid >> 2;        // u-group 0..63 (16 u each)
  const int ub   = cg * 16;

  __shared__ float zsh[4 * 16 * 66]; // [wave][row][gate*16+u], pad 66

  // ---- phase 0: convert x to bf16 once (grid-stride) ----
  {
    const f32x4* xv = reinterpret_cast<const f32x4*>(x);
    short8* xo = reinterpret_cast<short8*>(xbf);
    const size_t nvec = (size_t)cB * cT * cD / 8;
    for (size_t i = (size_t)bid * NT + tid; i < nvec; i += (size_t)NBLK * NT) {
      f32x4 v0 = xv[2 * i];
      f32x4 v1 = xv[2 * i + 1];
      short8 s;
      s[0] = f2bf(v0[0]); s[1] = f2bf(v0[1]); s[2] = f2bf(v0[2]); s[3] = f2bf(v0[3]);
      s[4] = f2bf(v1[0]); s[5] = f2bf(v1[1]); s[6] = f2bf(v1[2]); s[7] = f2bf(v1[3]);
      xo[i] = s;
    }
  }

  // ---- time-invariant W fragments: Bf[i][g], kc = wv + 4*i, i=0..11 ----
  // B[k][n]: n = lane&15 col-in-tile, k = quad*8 + j. Gate g col = g*cU+ub+n.
  short8 Bf[12][4];
  #pragma unroll
  for (int i = 0; i < 12; ++i) {
    const int kc = wv + 4 * i;
    const int k0 = kc * 32 + quad * 8;
    #pragma unroll
    for (int g = 0; g < 4; ++g) {
      const int col = g * cU + ub + n;
      short8 b;
      #pragma unroll
      for (int j = 0; j < 8; ++j) {
        const int k = k0 + j;
        const float wgt = (k < cD) ? wk[(size_t)k * cG + col]
                                   : wr[(size_t)(k - cD) * cG + col];
        b[j] = f2bf(wgt);
      }
      Bf[i][g] = b;
    }
  }

  // ---- distributed epilogue mapping: thread -> (row, single u) ----
  const int erow = tid >> 4;        // 0..15
  const int eu   = tid & 15;        // 0..15
  const int hrow = mt * 16 + erow;  // global batch row this thread publishes
  const float bi  = bias[0 * cU + ub + eu];
  const float bff = bias[1 * cU + ub + eu];
  const float bc  = bias[2 * cU + ub + eu];
  const float bo  = bias[3 * cU + ub + eu];
  float cst = 0.0f;

  // A-frag addressing for x: A[m][k], m = n -> batch row, k = quad*8+j
  const int brow = mt * 16 + n;
  const short* xrow = xbf + (size_t)brow * cT * cD + quad * 8;

  // ---- initial full-grid barrier: xbf ready everywhere ----
  __builtin_amdgcn_fence(__ATOMIC_RELEASE, "agent");
  __syncthreads();
  if (tid == 0)
    __hip_atomic_store(flags + bid * 16, 1u, __ATOMIC_RELEASE,
                       __HIP_MEMORY_SCOPE_AGENT);
  if (wv == 0) {
    #pragma unroll
    for (int j = 0; j < 4; ++j) {
      const unsigned* fp = flags + (j * 64 + lane) * 16;
      while (__hip_atomic_load(fp, __ATOMIC_RELAXED,
                               __HIP_MEMORY_SCOPE_AGENT) < 1u) {}
    }
  }
  __syncthreads();
  __builtin_amdgcn_fence(__ATOMIC_ACQUIRE, "agent");

  const unsigned long long* hxu =
      reinterpret_cast<const unsigned long long*>(hx);
  const int mygrp = mt * 4 + (cg >> 4);   // this block's producer counter

  for (int t = 0; t < cT; ++t) {
    f32x4 acc[4] = {{0,0,0,0},{0,0,0,0},{0,0,0,0},{0,0,0,0}};

    // x-part (h-independent): kc = wv + 4*i, i=0..3 (kc < 16)
    const short* xr = xrow + (size_t)t * cD;
    #pragma unroll
    for (int i = 0; i < 4; ++i) {
      short8 af = *reinterpret_cast<const short8*>(xr + (wv + 4 * i) * 32);
      #pragma unroll
      for (int g = 0; g < 4; ++g) acc[g] = mfma16(af, Bf[i][g], acc[g]);
    }

    if (t > 0) {
      // ---- wait all 4 arrival counters (tiny poll footprint) ----
      if (lane < 4) {
        const unsigned* cp = cnt + (mt * 4 + lane) * 32;
        const unsigned tgt = 16u * (unsigned)t;
        while (__hip_atomic_load(cp, __ATOMIC_RELAXED,
                                 __HIP_MEMORY_SCOPE_AGENT) < tgt) {}
      }
      asm volatile("" ::: "memory");   // compiler fence: no load hoisting

      // ---- h A-frags straight to registers (MALL-coherent 8B loads) ----
      // lane reads h[mt*16+n][k], k = (kc-16)*32 + quad*8 + j, kc = wv+16+4i
      const unsigned long long* hb =
          hxu + (size_t)((t - 1) & 1) * 16384 +
          (size_t)(mt * 16 + n) * 256 + quad * 2;
      unsigned long long hv[16];
      #pragma unroll
      for (int i = 0; i < 8; ++i) {
        const int off = (wv + 4 * i) * 8;
        hv[2 * i]     = __hip_atomic_load(hb + off,     __ATOMIC_RELAXED,
                                          __HIP_MEMORY_SCOPE_AGENT);
        hv[2 * i + 1] = __hip_atomic_load(hb + off + 1, __ATOMIC_RELAXED,
                                          __HIP_MEMORY_SCOPE_AGENT);
      }
      #pragma unroll
      for (int i = 0; i < 8; ++i) {
        union { unsigned long long q[2]; short8 s; } u_;
        u_.q[0] = hv[2 * i]; u_.q[1] = hv[2 * i + 1];
        #pragma unroll
        for (int g = 0; g < 4; ++g)
          acc[g] = mfma16(u_.s, Bf[4 + i][g], acc[g]);
      }
    }

    // ---- per-wave partial z to zsh plane wv ----
    // C/D layout: col = n, row = quad*4 + r
    #pragma unroll
    for (int g = 0; g < 4; ++g)
      #pragma unroll
      for (int r = 0; r < 4; ++r)
        zsh[(wv * 16 + quad * 4 + r) * 66 + g * 16 + n] = acc[g][r];
    __syncthreads();

    // ---- distributed epilogue: 1 u per thread; sum 4 wave-planes ----
    float z[4];
    #pragma unroll
    for (int g = 0; g < 4; ++g)
      z[g] = zsh[(erow) * 66 + g * 16 + eu] +
             zsh[(16 + erow) * 66 + g * 16 + eu] +
             zsh[(32 + erow) * 66 + g * 16 + eu] +
             zsh[(48 + erow) * 66 + g * 16 + eu];
    const float ig = sigm(z[0] + bi);
    const float fg = sigm(z[1] + bff);
    const float gg = tanh_(z[2] + bc);
    const float og = sigm(z[3] + bo);
    cst = fg * cst + ig * gg;
    const float h = og * tanh_(cst);

    if (t == cT - 1) {
      out[(size_t)hrow * cU + ub + eu] = h;
    } else {
      __hip_atomic_store(hx + (size_t)(t & 1) * 65536 +
                             (size_t)hrow * 1024 + ub + eu,
                         f2bf(h), __ATOMIC_RELAXED, __HIP_MEMORY_SCOPE_AGENT);
      // drain this wave's stores to the coherency point; barrier covers all
      // waves; then ONE add publishes the whole block. Barrier also protects
      // zsh(t) (WAR) for the next iteration.
      asm volatile("s_waitcnt vmcnt(0)" ::: "memory");
      __syncthreads();
      if (tid == 0)
        __hip_atomic_fetch_add(cnt + mygrp * 32, 1u, __ATOMIC_RELAXED,
                               __HIP_MEMORY_SCOPE_AGENT);
    }
  }
}

extern "C" void kernel_launch(void* const* d_in, const int* in_sizes, int n_in,
                              void* d_out, int out_size, void* d_ws, size_t ws_size,
                              hipStream_t stream) {
  const float* x    = (const float*)d_in[0];
  const float* wk   = (const float*)d_in[1];
  const float* wr   = (const float*)d_in[2];
  const float* bias = (const float*)d_in[3];
  float* out = (float*)d_out;

  char* ws = (char*)d_ws;
  unsigned* flags = (unsigned*)ws;                 // 256 slots x 64B = 16 KB
  unsigned* cnt   = (unsigned*)(ws + 16384);       // 16 counters x 128B = 2 KB
  short* hx  = (short*)(ws + 18432);               // 2 x [64][1024] bf16, 256 KB
  short* xbf = (short*)(ws + 18432 + 262144);      // x bf16, 32 MB

  // zero flags (startup barrier) + counters (monotonic arrival counts).
  hipMemsetAsync(ws, 0, 18432, stream);

  lstm_persist<<<dim3(NBLK), dim3(NT), 0, stream>>>(
      x, wk, wr, bias, out, xbf, hx, cnt, flags);
}

// Round 9
// 2156.546 us; speedup vs baseline: 2.0095x; 1.0445x over previous
//
#include <hip/hip_runtime.h>
#include <cstddef>

// LSTM: x[64,512,512] f32, kernel[512,4096] f32, rec_kernel[1024,4096] f32,
// bias[4096] f32 -> h_last[64,1024] f32.
// R7 (3rd submission; rounds 7-8 were infra failures): contiguous-publish +
// per-wave signal + decongested poll.
//  - h layout [cg][mt][r][u']: each block publishes ONE contiguous 512B burst
//    (full-line stores, fast vmcnt drain). Consumers still load h A-frags
//    register-direct from MALL.
//  - Per-wave publish: store -> vmcnt(0) -> lane0 fetch_add (counter target
//    64*t). Producer __syncthreads eliminated -> 1 barrier/step.
//  - Poll: wave0 lanes 0-3 poll 4 counters with s_sleep backoff (R6 had 256
//    waves/mt hammering the MALL lines); waves 1-3 released via LDS epoch
//    flag (monotonic, no reset).
//  - Safety: pass wait(t+1) => all same-mt waves' add(t) => their epilogue(t)
//    zsh reads + barrier(t) done => zsh overwrite safe, barriers can't skew,
//    hx buf[t&1] overwrite safe (its readers finished step t-1 h-loads).

namespace {
constexpr int cB = 64;
constexpr int cT = 512;
constexpr int cD = 512;
constexpr int cU = 1024;
constexpr int cG = 4096;   // 4*U
constexpr int NBLK = 256;
constexpr int NT = 256;
}

typedef __attribute__((ext_vector_type(8))) short   short8;
typedef __attribute__((ext_vector_type(8))) __bf16  bf16x8;
typedef __attribute__((ext_vector_type(4))) float   f32x4;

__device__ inline short f2bf(float f) {
  unsigned u = __float_as_uint(f);
  u += 0x7fffu + ((u >> 16) & 1u);   // round-to-nearest-even
  return (short)(u >> 16);
}

__device__ inline f32x4 mfma16(short8 a, short8 b, f32x4 c) {
  return __builtin_amdgcn_mfma_f32_16x16x32_bf16(
      __builtin_bit_cast(bf16x8, a), __builtin_bit_cast(bf16x8, b), c, 0, 0, 0);
}

__device__ inline float sigm(float x) { return 1.0f / (1.0f + __expf(-x)); }
__device__ inline float tanh_(float x) {
  float a = fabsf(x);
  float e = __expf(-2.0f * a);
  float t = (1.0f - e) / (1.0f + e);
  return x < 0.0f ? -t : t;
}

__global__ __launch_bounds__(NT, 1) void lstm_persist(
    const float* __restrict__ x, const float* __restrict__ wk,
    const float* __restrict__ wr, const float* __restrict__ bias,
    float* __restrict__ out, short* __restrict__ xbf,
    short* hx, unsigned* cnt, unsigned* flags) {
  const int tid  = threadIdx.x;
  const int wv   = tid >> 6;        // wave = K-slice owner (kc === wv mod 4)
  const int lane = tid & 63;
  const int n    = lane & 15;       // MFMA A row m / C col
  const int quad = lane >> 4;
  const int bid  = blockIdx.x;
  const int mt   = bid & 3;         // batch m-tile (16 rows each)
  const int cg   = bid >> 2;        // u-group 0..63 (16 u each)
  const int ub   = cg * 16;

  __shared__ float zsh[4 * 16 * 66]; // [wave][row][gate*16+u], pad 66
  __shared__ unsigned go_flag;       // LDS epoch relay (monotonic)

  if (tid == 0) go_flag = 0u;

  // ---- phase 0: convert x to bf16 once (grid-stride) ----
  {
    const f32x4* xv = reinterpret_cast<const f32x4*>(x);
    short8* xo = reinterpret_cast<short8*>(xbf);
    const size_t nvec = (size_t)cB * cT * cD / 8;
    for (size_t i = (size_t)bid * NT + tid; i < nvec; i += (size_t)NBLK * NT) {
      f32x4 v0 = xv[2 * i];
      f32x4 v1 = xv[2 * i + 1];
      short8 s;
      s[0] = f2bf(v0[0]); s[1] = f2bf(v0[1]); s[2] = f2bf(v0[2]); s[3] = f2bf(v0[3]);
      s[4] = f2bf(v1[0]); s[5] = f2bf(v1[1]); s[6] = f2bf(v1[2]); s[7] = f2bf(v1[3]);
      xo[i] = s;
    }
  }

  // ---- time-invariant W fragments: Bf[i][g], kc = wv + 4*i, i=0..11 ----
  // B[k][n]: n = lane&15 col-in-tile, k = quad*8 + j. Gate g col = g*cU+ub+n.
  short8 Bf[12][4];
  #pragma unroll
  for (int i = 0; i < 12; ++i) {
    const int kc = wv + 4 * i;
    const int k0 = kc * 32 + quad * 8;
    #pragma unroll
    for (int g = 0; g < 4; ++g) {
      const int col = g * cU + ub + n;
      short8 b;
      #pragma unroll
      for (int j = 0; j < 8; ++j) {
        const int k = k0 + j;
        const float wgt = (k < cD) ? wk[(size_t)k * cG + col]
                                   : wr[(size_t)(k - cD) * cG + col];
        b[j] = f2bf(wgt);
      }
      Bf[i][g] = b;
    }
  }

  // ---- distributed epilogue mapping: thread -> (row, single u) ----
  const int erow = tid >> 4;        // 0..15
  const int eu   = tid & 15;        // 0..15
  const int hrow = mt * 16 + erow;  // global batch row this thread owns
  const float bi  = bias[0 * cU + ub + eu];
  const float bff = bias[1 * cU + ub + eu];
  const float bc  = bias[2 * cU + ub + eu];
  const float bo  = bias[3 * cU + ub + eu];
  float cst = 0.0f;

  // A-frag addressing for x: A[m][k], m = n -> batch row, k = quad*8+j
  const int brow = mt * 16 + n;
  const short* xrow = xbf + (size_t)brow * cT * cD + quad * 8;

  // ---- initial full-grid barrier: xbf ready everywhere ----
  __builtin_amdgcn_fence(__ATOMIC_RELEASE, "agent");
  __syncthreads();
  if (tid == 0)
    __hip_atomic_store(flags + bid * 16, 1u, __ATOMIC_RELEASE,
                       __HIP_MEMORY_SCOPE_AGENT);
  if (wv == 0) {
    #pragma unroll
    for (int j = 0; j < 4; ++j) {
      const unsigned* fp = flags + (j * 64 + lane) * 16;
      while (__hip_atomic_load(fp, __ATOMIC_RELAXED,
                               __HIP_MEMORY_SCOPE_AGENT) < 1u) {}
    }
  }
  __syncthreads();
  __builtin_amdgcn_fence(__ATOMIC_ACQUIRE, "agent");

  const unsigned long long* hxu =
      reinterpret_cast<const unsigned long long*>(hx);
  const int mygrp = mt * 4 + (cg >> 4);   // this block's producer counter
  // consumer h-load base (ull units): layout [buf][cg'][mt][r][u'] bf16,
  // u = (wv+4i)*32 + quad*8 + j  ->  ull idx = (wv+4i)*512 + (quad>>1)*256
  //                                          + mt*64 + n*4 + (quad&1)*2 + jj
  const unsigned long long* hbase =
      hxu + (size_t)(quad >> 1) * 256 + (size_t)mt * 64 + (size_t)n * 4 +
      (size_t)(quad & 1) * 2;

  for (int t = 0; t < cT; ++t) {
    f32x4 acc[4] = {{0,0,0,0},{0,0,0,0},{0,0,0,0},{0,0,0,0}};

    // x-part (h-independent): kc = wv + 4*i, i=0..3 (kc < 16)
    const short* xr = xrow + (size_t)t * cD;
    #pragma unroll
    for (int i = 0; i < 4; ++i) {
      short8 af = *reinterpret_cast<const short8*>(xr + (wv + 4 * i) * 32);
      #pragma unroll
      for (int g = 0; g < 4; ++g) acc[g] = mfma16(af, Bf[i][g], acc[g]);
    }

    if (t > 0) {
      // ---- arrival wait: wave0 polls MALL counters w/ backoff; others
      //      spin on the LDS epoch flag (no MALL traffic) ----
      if (wv == 0) {
        if (lane < 4) {
          const unsigned* cp = cnt + (mt * 4 + lane) * 32;
          const unsigned tgt = 64u * (unsigned)t;
          while (__hip_atomic_load(cp, __ATOMIC_RELAXED,
                                   __HIP_MEMORY_SCOPE_AGENT) < tgt)
            __builtin_amdgcn_s_sleep(1);
        }
        __hip_atomic_store(&go_flag, (unsigned)t, __ATOMIC_RELEASE,
                           __HIP_MEMORY_SCOPE_WORKGROUP);
      } else {
        while (__hip_atomic_load(&go_flag, __ATOMIC_ACQUIRE,
                                 __HIP_MEMORY_SCOPE_WORKGROUP) < (unsigned)t) {}
      }
      asm volatile("" ::: "memory");   // no load hoisting above the wait

      // ---- h A-frags straight to registers (contiguous-block layout) ----
      const unsigned long long* hb = hbase + (size_t)((t - 1) & 1) * 16384;
      unsigned long long hv[16];
      #pragma unroll
      for (int i = 0; i < 8; ++i) {
        const int off = (wv + 4 * i) * 512;
        hv[2 * i]     = __hip_atomic_load(hb + off,     __ATOMIC_RELAXED,
                                          __HIP_MEMORY_SCOPE_AGENT);
        hv[2 * i + 1] = __hip_atomic_load(hb + off + 1, __ATOMIC_RELAXED,
                                          __HIP_MEMORY_SCOPE_AGENT);
      }
      #pragma unroll
      for (int i = 0; i < 8; ++i) {
        union { unsigned long long q[2]; short8 s; } u_;
        u_.q[0] = hv[2 * i]; u_.q[1] = hv[2 * i + 1];
        #pragma unroll
        for (int g = 0; g < 4; ++g)
          acc[g] = mfma16(u_.s, Bf[4 + i][g], acc[g]);
      }
    }

    // ---- per-wave partial z to zsh plane wv (own plane only) ----
    // C/D layout: col = n, row = quad*4 + r
    #pragma unroll
    for (int g = 0; g < 4; ++g)
      #pragma unroll
      for (int r = 0; r < 4; ++r)
        zsh[(wv * 16 + quad * 4 + r) * 66 + g * 16 + n] = acc[g][r];
    __syncthreads();   // the ONLY barrier per step

    // ---- distributed epilogue: 1 u per thread; sum 4 wave-planes ----
    float z[4];
    #pragma unroll
    for (int g = 0; g < 4; ++g)
      z[g] = zsh[(erow) * 66 + g * 16 + eu] +
             zsh[(16 + erow) * 66 + g * 16 + eu] +
             zsh[(32 + erow) * 66 + g * 16 + eu] +
             zsh[(48 + erow) * 66 + g * 16 + eu];
    const float ig = sigm(z[0] + bi);
    const float fg = sigm(z[1] + bff);
    const float gg = tanh_(z[2] + bc);
    const float og = sigm(z[3] + bo);
    cst = fg * cst + ig * gg;
    const float h = og * tanh_(cst);

    if (t == cT - 1) {
      out[(size_t)hrow * cU + ub + eu] = h;
    } else {
      // contiguous 512B block publish: thread tid -> base + tid
      __hip_atomic_store(hx + (size_t)(t & 1) * 65536 +
                             (size_t)(cg * 4 + mt) * 256 + tid,
                         f2bf(h), __ATOMIC_RELAXED, __HIP_MEMORY_SCOPE_AGENT);
      // per-wave drain + signal: no block barrier on the publish path
      asm volatile("s_waitcnt vmcnt(0)" ::: "memory");
      if (lane == 0)
        __hip_atomic_fetch_add(cnt + mygrp * 32, 1u, __ATOMIC_RELAXED,
                               __HIP_MEMORY_SCOPE_AGENT);
    }
  }
}

extern "C" void kernel_launch(void* const* d_in, const int* in_sizes, int n_in,
                              void* d_out, int out_size, void* d_ws, size_t ws_size,
                              hipStream_t stream) {
  const float* x    = (const float*)d_in[0];
  const float* wk   = (const float*)d_in[1];
  const float* wr   = (const float*)d_in[2];
  const float* bias = (const float*)d_in[3];
  float* out = (float*)d_out;

  char* ws = (char*)d_ws;
  unsigned* flags = (unsigned*)ws;                 // 256 slots x 64B = 16 KB
  unsigned* cnt   = (unsigned*)(ws + 16384);       // 16 counters x 128B = 2 KB
  short* hx  = (short*)(ws + 18432);               // 2 x 128KB bf16 h buffers
  short* xbf = (short*)(ws + 18432 + 262144);      // x bf16, 32 MB

  // zero flags (startup barrier) + counters (monotonic arrival counts).
  hipMemsetAsync(ws, 0, 18432, stream);

  lstm_persist<<<dim3(NBLK), dim3(NT), 0, stream>>>(
      x, wk, wr, bias, out, xbf, hx, cnt, flags);
}